// Round 2
// baseline (6744.503 us; speedup 1.0000x reference)
//
#include <hip/hip_runtime.h>
#include <math.h>
#include <stdint.h>

#define B_    4096
#define SEQ_  19
#define E_    128
#define H_    1920
#define G4_   7680          // 4*H
#define KDIM  2176          // 2E + H
#define N2_   20

#define BM    256
#define BK    64
#define NT    (KDIM / BK)   // 34

typedef __attribute__((ext_vector_type(8))) short bf16x8;
typedef __attribute__((ext_vector_type(4))) float f32x4;

__device__ __forceinline__ unsigned short f2bf(float f) {
  union { float f; unsigned int u; } v; v.f = f;
  unsigned int u = v.u;
  u += 0x7fffu + ((u >> 16) & 1u);   // RNE
  return (unsigned short)(u >> 16);
}
__device__ __forceinline__ float bf2f(unsigned short s) {
  union { unsigned int u; float f; } v; v.u = ((unsigned int)s) << 16;
  return v.f;
}
__device__ __forceinline__ float sigm(float x) { return 1.f / (1.f + __expf(-x)); }
__device__ __forceinline__ float tanh_fast(float x) {
  float ax = fabsf(x);
  float t = __expf(-2.f * ax);
  float r = (1.f - t) / (1.f + t);
  return copysignf(r, x);
}

// ---- weight permute + f32->bf16: W_perm[4u+g][k] = (k<256 ? W_ih : W_hh)[g*H+u][...]
__global__ __launch_bounds__(256) void wperm_kernel(const float* __restrict__ Wih,
                                                    const float* __restrict__ Whh,
                                                    unsigned short* __restrict__ Wp) {
  int k = blockIdx.x * 256 + threadIdx.x;
  int r = blockIdx.y;
  if (k >= KDIM) return;
  int u = r >> 2, g = r & 3;
  int orow = g * H_ + u;
  float v = (k < 256) ? Wih[(size_t)orow * 256 + k] : Whh[(size_t)orow * H_ + (k - 256)];
  Wp[(size_t)r * KDIM + k] = f2bf(v);
}

__global__ __launch_bounds__(256) void bias_kernel(const float* __restrict__ bi,
                                                   const float* __restrict__ bh,
                                                   float* __restrict__ bp) {
  int r = blockIdx.x * 256 + threadIdx.x;
  if (r >= G4_) return;
  int u = r >> 2, g = r & 3;
  int orow = g * H_ + u;
  bp[r] = bi[orow] + bh[orow];
}

// zero the h-region of A buffer (h0 = 0)
__global__ __launch_bounds__(256) void zeroh_kernel(unsigned short* __restrict__ Ab) {
  int u = blockIdx.x * 256 + threadIdx.x;
  if (u >= H_) return;
  Ab[(size_t)blockIdx.y * KDIM + 256 + u] = 0;
}

// write x_t = [emb(input1[b,t]) | pos[t]] (bf16) into A[:, 0:256]
__global__ __launch_bounds__(256) void copyx_kernel(const int* __restrict__ in1,
                                                    const float* __restrict__ emb,
                                                    const float* __restrict__ pos,
                                                    unsigned short* __restrict__ Adst, int t) {
  int b = blockIdx.x, e = threadIdx.x;
  float v;
  if (e < 128) v = emb[(size_t)in1[b * SEQ_ + t] * E_ + e];
  else         v = pos[t * E_ + (e - 128)];
  Adst[(size_t)b * KDIM + e] = f2bf(v);
}

// ---- fused gates GEMM + LSTM cell epilogue ----
// 256x256 tile, 8 waves (2M x 4N), BK=64, double-buffered LDS, 2-phase schedule.
// C(4096,7680) = A(4096,2176)bf16 @ W_perm(7680,2176)^T + bias; per unit:
// i,f,g,o -> c' = f*c + i*g ; h = o*tanh(c') ; h(bf16) -> Anext[:,256+u]
__global__ __launch_bounds__(512, 2) void gemm_lstm_kernel(
    const unsigned short* __restrict__ A,
    const unsigned short* __restrict__ W,
    const float* __restrict__ bias,
    float* __restrict__ Cst,
    unsigned short* __restrict__ Anext,
    int t0) {
  __shared__ __align__(16) unsigned short lds[2][2][BM * BK];  // [buf][A=0/B=1]
  const int tid  = threadIdx.x;
  const int lane = tid & 63, wid = tid >> 6;
  const int wm = wid >> 2, wn = wid & 3;       // 2x4 waves; per-wave out 128x64
  const int lr = lane & 15, lk = lane >> 4;

  // T1: bijective XCD swizzle (480 % 8 == 0), M-fastest decode
  const int bid = blockIdx.x;
  const int swz = (bid & 7) * 60 + (bid >> 3);
  const int m0 = (swz & 15) * BM;       // 16 M-blocks
  const int n0 = (swz >> 4) * BM;       // 30 N-blocks

  f32x4 acc[8][4];
#pragma unroll
  for (int i = 0; i < 8; ++i)
#pragma unroll
    for (int j = 0; j < 4; ++j) acc[i][j] = (f32x4){0.f, 0.f, 0.f, 0.f};

#define STAGE(bufi, kt) do {                                                        \
    _Pragma("unroll")                                                               \
    for (int r_ = 0; r_ < 4; ++r_) {                                                \
      int fi_ = r_ * 512 + tid;                                                     \
      int row_ = fi_ >> 3, c8_ = fi_ & 7;                                           \
      const unsigned short* ga_ = &A[(size_t)(m0 + row_) * KDIM + (kt) * 64 + c8_ * 8]; \
      const unsigned short* gb_ = &W[(size_t)(n0 + row_) * KDIM + (kt) * 64 + c8_ * 8]; \
      __builtin_amdgcn_global_load_lds((const __attribute__((address_space(1))) void*)ga_, \
          (__attribute__((address_space(3))) void*)&lds[bufi][0][fi_ * 8], 16, 0, 0);   \
      __builtin_amdgcn_global_load_lds((const __attribute__((address_space(1))) void*)gb_, \
          (__attribute__((address_space(3))) void*)&lds[bufi][1][fi_ * 8], 16, 0, 0);   \
    }                                                                               \
  } while (0)

  int cur = 0;
  STAGE(0, 0);
  __syncthreads();   // vmcnt(0) + barrier: buf0 ready

  for (int kt = 0; kt < NT; ++kt) {
    if (kt + 1 < NT) STAGE(cur ^ 1, kt + 1);   // issue next-tile loads first
#pragma unroll
    for (int ks = 0; ks < 2; ++ks) {
      bf16x8 af[8], bfr[4];
#pragma unroll
      for (int mi = 0; mi < 8; ++mi)
        af[mi] = *(const bf16x8*)&lds[cur][0][(wm * 128 + mi * 16 + lr) * 64 + ks * 32 + lk * 8];
#pragma unroll
      for (int ni = 0; ni < 4; ++ni)
        bfr[ni] = *(const bf16x8*)&lds[cur][1][(wn * 64 + ni * 16 + lr) * 64 + ks * 32 + lk * 8];
      __builtin_amdgcn_s_setprio(1);
#pragma unroll
      for (int mi = 0; mi < 8; ++mi)
#pragma unroll
        for (int ni = 0; ni < 4; ++ni)
          acc[mi][ni] = __builtin_amdgcn_mfma_f32_16x16x32_bf16(af[mi], bfr[ni], acc[mi][ni], 0, 0, 0);
      __builtin_amdgcn_s_setprio(0);
    }
    __syncthreads();   // vmcnt(0) (staging landed) + lgkmcnt + barrier
    cur ^= 1;
  }

  // epilogue: interleaved gate columns (col = 4u+g); exchange within 4-lane groups
  const int mbase = m0 + wm * 128;
  const int bl = lane & ~3;
#pragma unroll
  for (int ni = 0; ni < 4; ++ni) {
    int colg = n0 + wn * 64 + ni * 16 + lr;
    float bn = bias[colg];
    int ug = colg >> 2;   // identical across the 4-lane group
#pragma unroll
    for (int mi = 0; mi < 8; ++mi) {
#pragma unroll
      for (int r = 0; r < 4; ++r) {
        float v = acc[mi][ni][r] + bn;
        float gi = __shfl(v, bl + 0);
        float gf = __shfl(v, bl + 1);
        float gg = __shfl(v, bl + 2);
        float go = __shfl(v, bl + 3);
        int mg = mbase + mi * 16 + lk * 4 + r;
        float cold = t0 ? 0.f : Cst[(size_t)mg * H_ + ug];
        float ii = sigm(gi), ff = sigm(gf);
        float gv = tanh_fast(gg), oo = sigm(go);
        float cn = ff * cold + ii * gv;
        float hh = oo * tanh_fast(cn);
        if ((lane & 3) == 0) {
          Cst[(size_t)mg * H_ + ug] = cn;
          Anext[(size_t)mg * KDIM + 256 + ug] = f2bf(hh);
        }
      }
    }
  }
}

// ---- final: per-row einsum + max + 2-class log-softmax ----
__global__ __launch_bounds__(64) void final_kernel(const unsigned short* __restrict__ Ah,
                                                   const int* __restrict__ in2,
                                                   const float* __restrict__ emb,
                                                   const float* __restrict__ linw,
                                                   const float* __restrict__ linb,
                                                   float* __restrict__ out) {
  __shared__ float hrow[H_];
  __shared__ float etab[N2_][E_];
  __shared__ float dlds[5][3][N2_];
  int b = blockIdx.x, l = threadIdx.x;

  for (int u = l; u < H_; u += 64) hrow[u] = bf2f(Ah[(size_t)b * KDIM + 256 + u]);
  for (int m = 0; m < N2_; ++m) {
    int idx = in2[b * N2_ + m];
    for (int e = l; e < E_; e += 64) etab[m][e] = emb[(size_t)idx * E_ + e];
  }
  __syncthreads();

  for (int cc = l; cc < 300; cc += 64) {
    int k = cc / 60, rem = cc % 60;
    int j = rem / 20, m = rem % 20;
    float s = 0.f;
    const float* hp = &hrow[k * 384 + j * 128];
#pragma unroll 4
    for (int e = 0; e < 128; ++e) s += hp[e] * etab[m][e];
    dlds[k][j][m] = s;
  }
  __syncthreads();

  float mx = -INFINITY;
  for (int cc = l; cc < 90; cc += 64) {
    int k = cc / 18, n = cc % 18;
    float rs = dlds[k][0][n] + dlds[k][1][n + 1] + dlds[k][2][n + 2];
    mx = fmaxf(mx, rs);
  }
#pragma unroll
  for (int off = 32; off; off >>= 1) mx = fmaxf(mx, __shfl_xor(mx, off));

  if (l == 0) {
    float z0 = mx * linw[0] + linb[0];
    float z1 = mx * linw[1] + linb[1];
    float zm = fmaxf(z0, z1);
    float lse = zm + logf(expf(z0 - zm) + expf(z1 - zm));
    out[b * 2 + 0] = z0 - lse;
    out[b * 2 + 1] = z1 - lse;
  }
}

extern "C" void kernel_launch(void* const* d_in, const int* in_sizes, int n_in,
                              void* d_out, int out_size, void* d_ws, size_t ws_size,
                              hipStream_t stream) {
  (void)in_sizes; (void)n_in; (void)out_size; (void)ws_size;
  const int*   in1  = (const int*)d_in[0];
  const int*   in2  = (const int*)d_in[1];
  const float* emb  = (const float*)d_in[2];
  const float* pos  = (const float*)d_in[3];
  const float* Wih  = (const float*)d_in[4];
  const float* Whh  = (const float*)d_in[5];
  const float* bih  = (const float*)d_in[6];
  const float* bhh  = (const float*)d_in[7];
  const float* linw = (const float*)d_in[8];
  const float* linb = (const float*)d_in[9];
  float* out = (float*)d_out;

  char* ws = (char*)d_ws;
  const size_t WPERM_B = (size_t)G4_ * KDIM * 2;   // 33,423,360
  const size_t ABUF_B  = (size_t)B_ * KDIM * 2;    // 17,825,792
  const size_t CST_B   = (size_t)B_ * H_ * 4;      // 31,457,280
  unsigned short* Wp  = (unsigned short*)(ws);
  unsigned short* A0  = (unsigned short*)(ws + WPERM_B);
  unsigned short* A1  = (unsigned short*)(ws + WPERM_B + ABUF_B);
  float*          Cst = (float*)(ws + WPERM_B + 2 * ABUF_B);
  float*          bp  = (float*)(ws + WPERM_B + 2 * ABUF_B + CST_B);

  // prep (must rerun every call: ws is re-poisoned)
  wperm_kernel<<<dim3(9, G4_), 256, 0, stream>>>(Wih, Whh, Wp);
  bias_kernel<<<dim3((G4_ + 255) / 256), 256, 0, stream>>>(bih, bhh, bp);
  zeroh_kernel<<<dim3(8, B_), 256, 0, stream>>>(A0);
  copyx_kernel<<<dim3(B_), 256, 0, stream>>>(in1, emb, pos, A0, 0);

  unsigned short* Abufs[2] = {A0, A1};
  for (int t = 0; t < SEQ_; ++t) {
    unsigned short* Acur = Abufs[t & 1];
    unsigned short* Anxt = Abufs[(t + 1) & 1];
    gemm_lstm_kernel<<<dim3((G4_ / BM) * (B_ / BM)), 512, 0, stream>>>(
        Acur, Wp, bp, Cst, Anxt, t == 0 ? 1 : 0);
    if (t + 1 < SEQ_)
      copyx_kernel<<<dim3(B_), 256, 0, stream>>>(in1, emb, pos, Anxt, t + 1);
  }
  final_kernel<<<dim3(B_), 64, 0, stream>>>(Abufs[SEQ_ & 1], in2, emb, linw, linb, out);
}

// Round 4
// 3110.797 us; speedup vs baseline: 2.1681x; 2.1681x over previous
//
#include <hip/hip_runtime.h>
#include <math.h>
#include <stdint.h>

#define B_    4096
#define SEQ_  19
#define E_    128
#define H_    1920
#define G4_   7680          // 4*H
#define KDIM  2176          // 2E + H
#define N2_   20

#define BM    256
#define BK    64
#define NT    (KDIM / BK)   // 34

typedef __attribute__((ext_vector_type(8))) short bf16x8;
typedef __attribute__((ext_vector_type(4))) float f32x4;

__device__ __forceinline__ unsigned short f2bf(float f) {
  union { float f; unsigned int u; } v; v.f = f;
  unsigned int u = v.u;
  u += 0x7fffu + ((u >> 16) & 1u);   // RNE
  return (unsigned short)(u >> 16);
}
__device__ __forceinline__ float bf2f(unsigned short s) {
  union { unsigned int u; float f; } v; v.u = ((unsigned int)s) << 16;
  return v.f;
}
__device__ __forceinline__ float sigm(float x) { return 1.f / (1.f + __expf(-x)); }
__device__ __forceinline__ float tanh_fast(float x) {
  float ax = fabsf(x);
  float t = __expf(-2.f * ax);
  float r = (1.f - t) / (1.f + t);
  return copysignf(r, x);
}

// ---- weight permute + f32->bf16: W_perm[4u+g][k] = (k<256 ? W_ih : W_hh)[g*H+u][...]
__global__ __launch_bounds__(256) void wperm_kernel(const float* __restrict__ Wih,
                                                    const float* __restrict__ Whh,
                                                    unsigned short* __restrict__ Wp) {
  int k = blockIdx.x * 256 + threadIdx.x;
  int r = blockIdx.y;
  if (k >= KDIM) return;
  int u = r >> 2, g = r & 3;
  int orow = g * H_ + u;
  float v = (k < 256) ? Wih[(size_t)orow * 256 + k] : Whh[(size_t)orow * H_ + (k - 256)];
  Wp[(size_t)r * KDIM + k] = f2bf(v);
}

__global__ __launch_bounds__(256) void bias_kernel(const float* __restrict__ bi,
                                                   const float* __restrict__ bh,
                                                   float* __restrict__ bp) {
  int r = blockIdx.x * 256 + threadIdx.x;
  if (r >= G4_) return;
  int u = r >> 2, g = r & 3;
  int orow = g * H_ + u;
  bp[r] = bi[orow] + bh[orow];
}

// zero the h-region of A buffer (h0 = 0)
__global__ __launch_bounds__(256) void zeroh_kernel(unsigned short* __restrict__ Ab) {
  int u = blockIdx.x * 256 + threadIdx.x;
  if (u >= H_) return;
  Ab[(size_t)blockIdx.y * KDIM + 256 + u] = 0;
}

// write x_t = [emb(input1[b,t]) | pos[t]] (bf16) into A[:, 0:256]
__global__ __launch_bounds__(256) void copyx_kernel(const int* __restrict__ in1,
                                                    const float* __restrict__ emb,
                                                    const float* __restrict__ pos,
                                                    unsigned short* __restrict__ Adst, int t) {
  int b = blockIdx.x, e = threadIdx.x;
  float v;
  if (e < 128) v = emb[(size_t)in1[b * SEQ_ + t] * E_ + e];
  else         v = pos[t * E_ + (e - 128)];
  Adst[(size_t)b * KDIM + e] = f2bf(v);
}

// ---- fused gates GEMM + LSTM cell epilogue ----
// 256x256 tile, 8 waves (2M x 4N), BK=64, double-buffered LDS, 2-phase schedule.
// T2 XOR-swizzled LDS (linear dest + pre-swizzled global source + swizzled ds_read).
// C(4096,7680) = A(4096,2176)bf16 @ W_perm(7680,2176)^T + bias; per unit:
// i,f,g,o -> c' = f*c + i*g ; h = o*tanh(c') ; h(bf16) -> Anext[:,256+u]
// Cst layout is TRANSPOSED: Cst[ug * B_ + mg] for coalesced epilogue access.
__global__ __launch_bounds__(512, 2) void gemm_lstm_kernel(
    const unsigned short* __restrict__ A,
    const unsigned short* __restrict__ W,
    const float* __restrict__ bias,
    float* __restrict__ Cst,
    unsigned short* __restrict__ Anext,
    int t0) {
  __shared__ __align__(16) unsigned short lds[2][2][BM * BK];  // [buf][A=0/B=1]
  const int tid  = threadIdx.x;
  const int lane = tid & 63, wid = tid >> 6;
  const int wm = wid >> 2, wn = wid & 3;       // 2x4 waves; per-wave out 128x64
  const int lr = lane & 15, lk = lane >> 4;

  // T1: bijective XCD swizzle (480 % 8 == 0)
  const int bid = blockIdx.x;
  const int swz = (bid & 7) * 60 + (bid >> 3);
  const int m0 = (swz & 15) * BM;       // 16 M-blocks
  const int n0 = (swz >> 4) * BM;       // 30 N-blocks

  f32x4 acc[8][4];
#pragma unroll
  for (int i = 0; i < 8; ++i)
#pragma unroll
    for (int j = 0; j < 4; ++j) acc[i][j] = (f32x4){0.f, 0.f, 0.f, 0.f};

  // T2: LDS dest linear; global source slot pre-swizzled with row&7.
#define STAGE(bufi, kt) do {                                                        \
    _Pragma("unroll")                                                               \
    for (int r_ = 0; r_ < 4; ++r_) {                                                \
      int fi_ = r_ * 512 + tid;                                                     \
      int row_ = fi_ >> 3, c8_ = fi_ & 7;                                           \
      int cs_ = c8_ ^ (row_ & 7);                                                   \
      const unsigned short* ga_ = &A[(size_t)(m0 + row_) * KDIM + (kt) * 64 + cs_ * 8]; \
      const unsigned short* gb_ = &W[(size_t)(n0 + row_) * KDIM + (kt) * 64 + cs_ * 8]; \
      __builtin_amdgcn_global_load_lds((const __attribute__((address_space(1))) void*)ga_, \
          (__attribute__((address_space(3))) void*)&lds[bufi][0][fi_ * 8], 16, 0, 0);   \
      __builtin_amdgcn_global_load_lds((const __attribute__((address_space(1))) void*)gb_, \
          (__attribute__((address_space(3))) void*)&lds[bufi][1][fi_ * 8], 16, 0, 0);   \
    }                                                                               \
  } while (0)

  int cur = 0;
  STAGE(0, 0);
  __syncthreads();   // vmcnt(0) + barrier: buf0 ready

  const int rsw = lr & 7;  // row&7 for all this lane's fragment rows
  for (int kt = 0; kt < NT; ++kt) {
    if (kt + 1 < NT) STAGE(cur ^ 1, kt + 1);   // issue next-tile loads first
#pragma unroll
    for (int ks = 0; ks < 2; ++ks) {
      const int slot = (ks * 4 + lk) ^ rsw;    // T2 swizzled 16B slot
      bf16x8 af[8], bfr[4];
#pragma unroll
      for (int mi = 0; mi < 8; ++mi)
        af[mi] = *(const bf16x8*)&lds[cur][0][(wm * 128 + mi * 16 + lr) * 64 + slot * 8];
#pragma unroll
      for (int ni = 0; ni < 4; ++ni)
        bfr[ni] = *(const bf16x8*)&lds[cur][1][(wn * 64 + ni * 16 + lr) * 64 + slot * 8];
      __builtin_amdgcn_s_setprio(1);
#pragma unroll
      for (int mi = 0; mi < 8; ++mi)
#pragma unroll
        for (int ni = 0; ni < 4; ++ni)
          acc[mi][ni] = __builtin_amdgcn_mfma_f32_16x16x32_bf16(af[mi], bfr[ni], acc[mi][ni], 0, 0, 0);
      __builtin_amdgcn_s_setprio(0);
    }
    __syncthreads();   // vmcnt(0) (staging landed) + lgkmcnt + barrier
    cur ^= 1;
  }

  // ---- epilogue ----
  // Gate columns interleaved (col = 4u+g). Lanes bl..bl+3 hold gates g=0..3 of unit ug.
  // Lane j = lane&3 owns cell r=j (all 64 lanes active).
  unsigned short* hbuf = &lds[0][0][0];   // reuse staging LDS: h_tile[256][64] bf16
  const int j = lane & 3;
  const int bl = lane & ~3;
  const int ugl_base = wn * 16 + (lr >> 2);             // + ni*4 below
#pragma unroll
  for (int ni = 0; ni < 4; ++ni) {
    int colg = n0 + wn * 64 + ni * 16 + lr;
    float bn = bias[colg];
    int ug = colg >> 2;                   // same across the 4-lane group
    int ugl = ugl_base + ni * 4;
#pragma unroll
    for (int mi = 0; mi < 8; ++mi) {
      float gi = 0.f, gf = 0.f, gg = 0.f, go = 0.f;
#pragma unroll
      for (int r = 0; r < 4; ++r) {
        float v = acc[mi][ni][r] + bn;
        float a0 = __shfl(v, bl + 0);
        float a1 = __shfl(v, bl + 1);
        float a2 = __shfl(v, bl + 2);
        float a3 = __shfl(v, bl + 3);
        bool sel = (j == r);
        gi = sel ? a0 : gi; gf = sel ? a1 : gf;
        gg = sel ? a2 : gg; go = sel ? a3 : go;
      }
      int mgl = wm * 128 + mi * 16 + lk * 4 + j;        // local row 0..255
      int mg = m0 + mgl;
      float cold = t0 ? 0.f : Cst[(size_t)ug * B_ + mg];
      float ii = sigm(gi), ff = sigm(gf);
      float gv = tanh_fast(gg), oo = sigm(go);
      float cn = ff * cold + ii * gv;
      float hh = oo * tanh_fast(cn);
      Cst[(size_t)ug * B_ + mg] = cn;                   // coalesced: 4x64B runs/wave
      hbuf[mgl * 64 + ugl] = f2bf(hh);
    }
  }
  __syncthreads();

  // cooperative coalesced h write: 256 rows x 64 ug (bf16) -> Anext cols 256+n0/4..
  {
    int row = tid >> 1, half = tid & 1;
    const unsigned short* src = &hbuf[row * 64 + half * 32];
    unsigned short* dst = &Anext[(size_t)(m0 + row) * KDIM + 256 + (n0 >> 2) + half * 32];
#pragma unroll
    for (int q = 0; q < 4; ++q)
      *(bf16x8*)&dst[q * 8] = *(const bf16x8*)&src[q * 8];
  }
}

// ---- final: per-row einsum + max + 2-class log-softmax ----
__global__ __launch_bounds__(64) void final_kernel(const unsigned short* __restrict__ Ah,
                                                   const int* __restrict__ in2,
                                                   const float* __restrict__ emb,
                                                   const float* __restrict__ linw,
                                                   const float* __restrict__ linb,
                                                   float* __restrict__ out) {
  __shared__ float hrow[H_];
  __shared__ float etab[N2_][E_];
  __shared__ float dlds[5][3][N2_];
  int b = blockIdx.x, l = threadIdx.x;

  for (int u = l; u < H_; u += 64) hrow[u] = bf2f(Ah[(size_t)b * KDIM + 256 + u]);
  for (int m = 0; m < N2_; ++m) {
    int idx = in2[b * N2_ + m];
    for (int e = l; e < E_; e += 64) etab[m][e] = emb[(size_t)idx * E_ + e];
  }
  __syncthreads();

  for (int cc = l; cc < 300; cc += 64) {
    int k = cc / 60, rem = cc % 60;
    int jj = rem / 20, m = rem % 20;
    float s = 0.f;
    const float* hp = &hrow[k * 384 + jj * 128];
#pragma unroll 4
    for (int e = 0; e < 128; ++e) s += hp[e] * etab[m][e];
    dlds[k][jj][m] = s;
  }
  __syncthreads();

  float mx = -INFINITY;
  for (int cc = l; cc < 90; cc += 64) {
    int k = cc / 18, n = cc % 18;
    float rs = dlds[k][0][n] + dlds[k][1][n + 1] + dlds[k][2][n + 2];
    mx = fmaxf(mx, rs);
  }
#pragma unroll
  for (int off = 32; off; off >>= 1) mx = fmaxf(mx, __shfl_xor(mx, off));

  if (l == 0) {
    float z0 = mx * linw[0] + linb[0];
    float z1 = mx * linw[1] + linb[1];
    float zm = fmaxf(z0, z1);
    float lse = zm + logf(expf(z0 - zm) + expf(z1 - zm));
    out[b * 2 + 0] = z0 - lse;
    out[b * 2 + 1] = z1 - lse;
  }
}

extern "C" void kernel_launch(void* const* d_in, const int* in_sizes, int n_in,
                              void* d_out, int out_size, void* d_ws, size_t ws_size,
                              hipStream_t stream) {
  (void)in_sizes; (void)n_in; (void)out_size; (void)ws_size;
  const int*   in1  = (const int*)d_in[0];
  const int*   in2  = (const int*)d_in[1];
  const float* emb  = (const float*)d_in[2];
  const float* pos  = (const float*)d_in[3];
  const float* Wih  = (const float*)d_in[4];
  const float* Whh  = (const float*)d_in[5];
  const float* bih  = (const float*)d_in[6];
  const float* bhh  = (const float*)d_in[7];
  const float* linw = (const float*)d_in[8];
  const float* linb = (const float*)d_in[9];
  float* out = (float*)d_out;

  char* ws = (char*)d_ws;
  const size_t WPERM_B = (size_t)G4_ * KDIM * 2;   // 33,423,360
  const size_t ABUF_B  = (size_t)B_ * KDIM * 2;    // 17,825,792
  const size_t CST_B   = (size_t)B_ * H_ * 4;      // 31,457,280
  unsigned short* Wp  = (unsigned short*)(ws);
  unsigned short* A0  = (unsigned short*)(ws + WPERM_B);
  unsigned short* A1  = (unsigned short*)(ws + WPERM_B + ABUF_B);
  float*          Cst = (float*)(ws + WPERM_B + 2 * ABUF_B);
  float*          bp  = (float*)(ws + WPERM_B + 2 * ABUF_B + CST_B);

  // prep (must rerun every call: ws is re-poisoned)
  wperm_kernel<<<dim3(9, G4_), 256, 0, stream>>>(Wih, Whh, Wp);
  bias_kernel<<<dim3((G4_ + 255) / 256), 256, 0, stream>>>(bih, bhh, bp);
  zeroh_kernel<<<dim3(8, B_), 256, 0, stream>>>(A0);
  copyx_kernel<<<dim3(B_), 256, 0, stream>>>(in1, emb, pos, A0, 0);

  unsigned short* Abufs[2] = {A0, A1};
  for (int t = 0; t < SEQ_; ++t) {
    unsigned short* Acur = Abufs[t & 1];
    unsigned short* Anxt = Abufs[(t + 1) & 1];
    gemm_lstm_kernel<<<dim3((G4_ / BM) * (B_ / BM)), 512, 0, stream>>>(
        Acur, Wp, bp, Cst, Anxt, t == 0 ? 1 : 0);
    if (t + 1 < SEQ_)
      copyx_kernel<<<dim3(B_), 256, 0, stream>>>(in1, emb, pos, Anxt, t + 1);
  }
  final_kernel<<<dim3(B_), 64, 0, stream>>>(Abufs[SEQ_ & 1], in2, emb, linw, linb, out);
}

// Round 6
// 2968.346 us; speedup vs baseline: 2.2721x; 1.0480x over previous
//
#include <hip/hip_runtime.h>
#include <math.h>
#include <stdint.h>

#define B_    4096
#define SEQ_  19
#define E_    128
#define H_    1920
#define G4_   7680          // 4*H
#define KDIM  2176          // 2E + H
#define N2_   20

#define BM    256
#define BK    64
#define NT    (KDIM / BK)   // 34

typedef __attribute__((ext_vector_type(8))) short bf16x8;
typedef __attribute__((ext_vector_type(4))) float f32x4;

__device__ __forceinline__ unsigned short f2bf(float f) {
  union { float f; unsigned int u; } v; v.f = f;
  unsigned int u = v.u;
  u += 0x7fffu + ((u >> 16) & 1u);   // RNE
  return (unsigned short)(u >> 16);
}
__device__ __forceinline__ float bf2f(unsigned short s) {
  union { unsigned int u; float f; } v; v.u = ((unsigned int)s) << 16;
  return v.f;
}
__device__ __forceinline__ float sigm(float x) { return 1.f / (1.f + __expf(-x)); }
__device__ __forceinline__ float tanh_fast(float x) {
  float ax = fabsf(x);
  float t = __expf(-2.f * ax);
  float r = (1.f - t) / (1.f + t);
  return copysignf(r, x);
}

// ---- weight permute + f32->bf16: W_perm[4u+g][k] = (k<256 ? W_ih : W_hh)[g*H+u][...]
__global__ __launch_bounds__(256) void wperm_kernel(const float* __restrict__ Wih,
                                                    const float* __restrict__ Whh,
                                                    unsigned short* __restrict__ Wp) {
  int k = blockIdx.x * 256 + threadIdx.x;
  int r = blockIdx.y;
  if (k >= KDIM) return;
  int u = r >> 2, g = r & 3;
  int orow = g * H_ + u;
  float v = (k < 256) ? Wih[(size_t)orow * 256 + k] : Whh[(size_t)orow * H_ + (k - 256)];
  Wp[(size_t)r * KDIM + k] = f2bf(v);
}

__global__ __launch_bounds__(256) void bias_kernel(const float* __restrict__ bi,
                                                   const float* __restrict__ bh,
                                                   float* __restrict__ bp) {
  int r = blockIdx.x * 256 + threadIdx.x;
  if (r >= G4_) return;
  int u = r >> 2, g = r & 3;
  int orow = g * H_ + u;
  bp[r] = bi[orow] + bh[orow];
}

// zero the h-region of A buffer (h0 = 0)
__global__ __launch_bounds__(256) void zeroh_kernel(unsigned short* __restrict__ Ab) {
  int u = blockIdx.x * 256 + threadIdx.x;
  if (u >= H_) return;
  Ab[(size_t)blockIdx.y * KDIM + 256 + u] = 0;
}

// write x_t = [emb(input1[b,t]) | pos[t]] (bf16) into A[:, 0:256]
__global__ __launch_bounds__(256) void copyx_kernel(const int* __restrict__ in1,
                                                    const float* __restrict__ emb,
                                                    const float* __restrict__ pos,
                                                    unsigned short* __restrict__ Adst, int t) {
  int b = blockIdx.x, e = threadIdx.x;
  float v;
  if (e < 128) v = emb[(size_t)in1[b * SEQ_ + t] * E_ + e];
  else         v = pos[t * E_ + (e - 128)];
  Adst[(size_t)b * KDIM + e] = f2bf(v);
}

// ---- fused gates GEMM + LSTM cell epilogue ----
// 256x256 tile, 8 waves (2M x 4N), BK=64, double-buffered LDS.
// 3-phase counted-vmcnt schedule (T3+T4): per phase {vmcnt(4)+s_barrier ->
// ds_read quadrant frags -> issue next-tile stage loads -> setprio MFMA}.
// Load order per tile: l0=A[0:64) l1=A[128:192) l2=Bg0h0 l3=Bg0h1
//                      l4=Bg1h0 l5=Bg1h1 l6=A[64:128) l7=A[192:256)
// chosen so vmcnt(4) at each phase proves exactly the rows that phase reads.
// T2 swizzle: LDS dest linear, global source 16B-slot ^= row&7, reads apply same XOR.
__global__ __launch_bounds__(512, 2) void gemm_lstm_kernel(
    const unsigned short* __restrict__ Ap,
    const unsigned short* __restrict__ Wp_,
    const float* __restrict__ bias,
    float* __restrict__ Cst,
    unsigned short* __restrict__ Anext,
    int t0) {
  __shared__ __align__(16) unsigned short lds[2][2][BM * BK];  // [buf][A=0/B=1]
  const int tid  = threadIdx.x;
  const int lane = tid & 63, wid = tid >> 6;
  const int wm = wid >> 2, wn = wid & 3;       // 2x4 waves; per-wave out 128x64
  const int lr = lane & 15, lk = lane >> 4;
  const int rsw = lr & 7;

  // T1: bijective XCD swizzle (480 % 8 == 0)
  const int bid = blockIdx.x;
  const int swz = (bid & 7) * 60 + (bid >> 3);
  const int m0 = (swz & 15) * BM;       // 16 M-blocks
  const int n0 = (swz >> 4) * BM;       // 30 N-blocks

  f32x4 acc[8][4];
#pragma unroll
  for (int i = 0; i < 8; ++i)
#pragma unroll
    for (int j = 0; j < 4; ++j) acc[i][j] = (f32x4){0.f, 0.f, 0.f, 0.f};

#define GLOAD(src, dst) __builtin_amdgcn_global_load_lds( \
    (const __attribute__((address_space(1))) void*)(src), \
    (__attribute__((address_space(3))) void*)(dst), 16, 0, 0)

  // A-stage: 64 rows starting at ab (1 VMEM inst/thread)
#define STAGE_A(bufi, kt, ab) do { \
    int row_ = (ab) + (tid >> 3); int c8_ = tid & 7; int cs_ = c8_ ^ (row_ & 7); \
    GLOAD(&Ap[(size_t)(m0 + row_) * KDIM + (size_t)(kt) * 64 + cs_ * 8], \
          &lds[bufi][0][row_ * 64 + c8_ * 8]); \
  } while (0)

  // B-stage: rows h*128 + (tid>=256)*64 + g*32 + ((tid&255)>>3)
#define STAGE_B(bufi, kt, g, h) do { \
    int row_ = (h) * 128 + ((tid >> 8) << 6) + (g) * 32 + ((tid & 255) >> 3); \
    int c8_ = tid & 7; int cs_ = c8_ ^ (row_ & 7); \
    GLOAD(&Wp_[(size_t)(n0 + row_) * KDIM + (size_t)(kt) * 64 + cs_ * 8], \
          &lds[bufi][1][row_ * 64 + c8_ * 8]); \
  } while (0)

#define VMBAR(n) do { asm volatile("s_waitcnt vmcnt(" #n ")" ::: "memory"); \
                      __builtin_amdgcn_s_barrier(); } while (0)

#define LDA_(mi_, ks_) (*(const bf16x8*)&lds[cur][0][(wm * 128 + (mi_) * 16 + lr) * 64 + ((((ks_) * 4 + lk) ^ rsw) * 8)])
#define LDB_(ni_, ks_) (*(const bf16x8*)&lds[cur][1][(wn * 64 + (ni_) * 16 + lr) * 64 + ((((ks_) * 4 + lk) ^ rsw) * 8)])

#define MFMA_(a_, b_, c_) __builtin_amdgcn_mfma_f32_16x16x32_bf16(a_, b_, c_, 0, 0, 0)

  // prologue: stage tile 0 (loads l0..l7 in canonical order)
  STAGE_A(0, 0, 0);   STAGE_A(0, 0, 128);
  STAGE_B(0, 0, 0, 0); STAGE_B(0, 0, 0, 1);
  STAGE_B(0, 0, 1, 0); STAGE_B(0, 0, 1, 1);
  STAGE_A(0, 0, 64);  STAGE_A(0, 0, 192);

  bf16x8 af[4][2], b0[2][2], b1[2][2];
  int cur = 0;

  for (int kt = 0; kt < NT - 1; ++kt) {
    const int nxt = cur ^ 1;
    // ---- phase 0: quadrant (mi 0-3, ni 0-1) ----
    VMBAR(4);   // tile-kt l0..l3 landed (A-lo rows, B-g0 rows)
#pragma unroll
    for (int mi = 0; mi < 4; ++mi) { af[mi][0] = LDA_(mi, 0); af[mi][1] = LDA_(mi, 1); }
#pragma unroll
    for (int ni = 0; ni < 2; ++ni) { b0[ni][0] = LDB_(ni, 0); b0[ni][1] = LDB_(ni, 1); }
    STAGE_A(nxt, kt + 1, 0); STAGE_A(nxt, kt + 1, 128);
    __builtin_amdgcn_s_setprio(1);
#pragma unroll
    for (int mi = 0; mi < 4; ++mi)
#pragma unroll
      for (int ni = 0; ni < 2; ++ni) {
        acc[mi][ni] = MFMA_(af[mi][0], b0[ni][0], acc[mi][ni]);
        acc[mi][ni] = MFMA_(af[mi][1], b0[ni][1], acc[mi][ni]);
      }
    __builtin_amdgcn_s_setprio(0);
    // ---- phase 1: quadrant (mi 0-3, ni 2-3) ----
    VMBAR(4);   // tile-kt l4,l5 landed (B-g1 rows)
#pragma unroll
    for (int ni = 0; ni < 2; ++ni) { b1[ni][0] = LDB_(2 + ni, 0); b1[ni][1] = LDB_(2 + ni, 1); }
    STAGE_B(nxt, kt + 1, 0, 0); STAGE_B(nxt, kt + 1, 0, 1);
    __builtin_amdgcn_s_setprio(1);
#pragma unroll
    for (int mi = 0; mi < 4; ++mi)
#pragma unroll
      for (int ni = 0; ni < 2; ++ni) {
        acc[mi][2 + ni] = MFMA_(af[mi][0], b1[ni][0], acc[mi][2 + ni]);
        acc[mi][2 + ni] = MFMA_(af[mi][1], b1[ni][1], acc[mi][2 + ni]);
      }
    __builtin_amdgcn_s_setprio(0);
    // ---- phase 2: quadrants (mi 4-7, ni 2-3) and (mi 4-7, ni 0-1) ----
    VMBAR(4);   // tile-kt l6,l7 landed (A-hi rows)
#pragma unroll
    for (int mi = 0; mi < 4; ++mi) { af[mi][0] = LDA_(4 + mi, 0); af[mi][1] = LDA_(4 + mi, 1); }
    STAGE_B(nxt, kt + 1, 1, 0); STAGE_B(nxt, kt + 1, 1, 1);
    __builtin_amdgcn_s_setprio(1);
#pragma unroll
    for (int mi = 0; mi < 4; ++mi)
#pragma unroll
      for (int ni = 0; ni < 2; ++ni) {
        acc[4 + mi][2 + ni] = MFMA_(af[mi][0], b1[ni][0], acc[4 + mi][2 + ni]);
        acc[4 + mi][2 + ni] = MFMA_(af[mi][1], b1[ni][1], acc[4 + mi][2 + ni]);
      }
    __builtin_amdgcn_s_setprio(0);
    STAGE_A(nxt, kt + 1, 64); STAGE_A(nxt, kt + 1, 192);
    __builtin_amdgcn_s_setprio(1);
#pragma unroll
    for (int mi = 0; mi < 4; ++mi)
#pragma unroll
      for (int ni = 0; ni < 2; ++ni) {
        acc[4 + mi][ni] = MFMA_(af[mi][0], b0[ni][0], acc[4 + mi][ni]);
        acc[4 + mi][ni] = MFMA_(af[mi][1], b0[ni][1], acc[4 + mi][ni]);
      }
    __builtin_amdgcn_s_setprio(0);
    cur = nxt;
  }

  // ---- tail tile (kt = NT-1): no staging, draining vmcnt ----
  VMBAR(4);
#pragma unroll
  for (int mi = 0; mi < 4; ++mi) { af[mi][0] = LDA_(mi, 0); af[mi][1] = LDA_(mi, 1); }
#pragma unroll
  for (int ni = 0; ni < 2; ++ni) { b0[ni][0] = LDB_(ni, 0); b0[ni][1] = LDB_(ni, 1); }
  __builtin_amdgcn_s_setprio(1);
#pragma unroll
  for (int mi = 0; mi < 4; ++mi)
#pragma unroll
    for (int ni = 0; ni < 2; ++ni) {
      acc[mi][ni] = MFMA_(af[mi][0], b0[ni][0], acc[mi][ni]);
      acc[mi][ni] = MFMA_(af[mi][1], b0[ni][1], acc[mi][ni]);
    }
  __builtin_amdgcn_s_setprio(0);
  VMBAR(2);
#pragma unroll
  for (int ni = 0; ni < 2; ++ni) { b1[ni][0] = LDB_(2 + ni, 0); b1[ni][1] = LDB_(2 + ni, 1); }
  __builtin_amdgcn_s_setprio(1);
#pragma unroll
  for (int mi = 0; mi < 4; ++mi)
#pragma unroll
    for (int ni = 0; ni < 2; ++ni) {
      acc[mi][2 + ni] = MFMA_(af[mi][0], b1[ni][0], acc[mi][2 + ni]);
      acc[mi][2 + ni] = MFMA_(af[mi][1], b1[ni][1], acc[mi][2 + ni]);
    }
  __builtin_amdgcn_s_setprio(0);
  VMBAR(0);
#pragma unroll
  for (int mi = 0; mi < 4; ++mi) { af[mi][0] = LDA_(4 + mi, 0); af[mi][1] = LDA_(4 + mi, 1); }
  __builtin_amdgcn_s_setprio(1);
#pragma unroll
  for (int mi = 0; mi < 4; ++mi)
#pragma unroll
    for (int ni = 0; ni < 2; ++ni) {
      acc[4 + mi][2 + ni] = MFMA_(af[mi][0], b1[ni][0], acc[4 + mi][2 + ni]);
      acc[4 + mi][2 + ni] = MFMA_(af[mi][1], b1[ni][1], acc[4 + mi][2 + ni]);
      acc[4 + mi][ni]     = MFMA_(af[mi][0], b0[ni][0], acc[4 + mi][ni]);
      acc[4 + mi][ni]     = MFMA_(af[mi][1], b0[ni][1], acc[4 + mi][ni]);
    }
  __builtin_amdgcn_s_setprio(0);

  // ---- epilogue ----
  // Gate columns interleaved (col = 4u+g). Lanes bl..bl+3 hold gates g=0..3 of unit ug.
  // Lane j = lane&3 owns cell r=j (all 64 lanes active).
  unsigned short* hbuf = &lds[0][0][0];   // buffer 0 A-region: dead (tail consumed buf 1)
  const int j = lane & 3;
  const int bl = lane & ~3;
  const int ugl_base = wn * 16 + (lr >> 2);             // + ni*4 below
#pragma unroll
  for (int ni = 0; ni < 4; ++ni) {
    int colg = n0 + wn * 64 + ni * 16 + lr;
    float bn = bias[colg];
    int ug = colg >> 2;                   // same across the 4-lane group
    int ugl = ugl_base + ni * 4;
#pragma unroll
    for (int mi = 0; mi < 8; ++mi) {
      float gi = 0.f, gf = 0.f, gg = 0.f, go = 0.f;
#pragma unroll
      for (int r = 0; r < 4; ++r) {
        float v = acc[mi][ni][r] + bn;
        float a0 = __shfl(v, bl + 0);
        float a1 = __shfl(v, bl + 1);
        float a2 = __shfl(v, bl + 2);
        float a3 = __shfl(v, bl + 3);
        bool sel = (j == r);
        gi = sel ? a0 : gi; gf = sel ? a1 : gf;
        gg = sel ? a2 : gg; go = sel ? a3 : go;
      }
      int mgl = wm * 128 + mi * 16 + lk * 4 + j;        // local row 0..255
      int mg = m0 + mgl;
      float cold = t0 ? 0.f : Cst[(size_t)ug * B_ + mg];
      float ii = sigm(gi), ff = sigm(gf);
      float gv = tanh_fast(gg), oo = sigm(go);
      float cn = ff * cold + ii * gv;
      float hh = oo * tanh_fast(cn);
      Cst[(size_t)ug * B_ + mg] = cn;                   // coalesced: 4x64B runs/wave
      hbuf[mgl * 64 + ugl] = f2bf(hh);
    }
  }
  __syncthreads();

  // cooperative coalesced h write: 256 rows x 64 ug (bf16) -> Anext cols 256+n0/4..
  {
    int row = tid >> 1, half = tid & 1;
    const unsigned short* src = &hbuf[row * 64 + half * 32];
    unsigned short* dst = &Anext[(size_t)(m0 + row) * KDIM + 256 + (n0 >> 2) + half * 32];
#pragma unroll
    for (int q = 0; q < 4; ++q)
      *(bf16x8*)&dst[q * 8] = *(const bf16x8*)&src[q * 8];
  }
#undef GLOAD
#undef STAGE_A
#undef STAGE_B
#undef VMBAR
#undef LDA_
#undef LDB_
#undef MFMA_
}

// ---- final: per-row einsum + max + 2-class log-softmax ----
__global__ __launch_bounds__(64) void final_kernel(const unsigned short* __restrict__ Ah,
                                                   const int* __restrict__ in2,
                                                   const float* __restrict__ emb,
                                                   const float* __restrict__ linw,
                                                   const float* __restrict__ linb,
                                                   float* __restrict__ out) {
  __shared__ float hrow[H_];
  __shared__ float etab[N2_][E_];
  __shared__ float dlds[5][3][N2_];
  int b = blockIdx.x, l = threadIdx.x;

  for (int u = l; u < H_; u += 64) hrow[u] = bf2f(Ah[(size_t)b * KDIM + 256 + u]);
  for (int m = 0; m < N2_; ++m) {
    int idx = in2[b * N2_ + m];
    for (int e = l; e < E_; e += 64) etab[m][e] = emb[(size_t)idx * E_ + e];
  }
  __syncthreads();

  for (int cc = l; cc < 300; cc += 64) {
    int k = cc / 60, rem = cc % 60;
    int jj = rem / 20, m = rem % 20;
    float s = 0.f;
    const float* hp = &hrow[k * 384 + jj * 128];
#pragma unroll 4
    for (int e = 0; e < 128; ++e) s += hp[e] * etab[m][e];
    dlds[k][jj][m] = s;
  }
  __syncthreads();

  float mx = -INFINITY;
  for (int cc = l; cc < 90; cc += 64) {
    int k = cc / 18, n = cc % 18;
    float rs = dlds[k][0][n] + dlds[k][1][n + 1] + dlds[k][2][n + 2];
    mx = fmaxf(mx, rs);
  }
#pragma unroll
  for (int off = 32; off; off >>= 1) mx = fmaxf(mx, __shfl_xor(mx, off));

  if (l == 0) {
    float z0 = mx * linw[0] + linb[0];
    float z1 = mx * linw[1] + linb[1];
    float zm = fmaxf(z0, z1);
    float lse = zm + logf(expf(z0 - zm) + expf(z1 - zm));
    out[b * 2 + 0] = z0 - lse;
    out[b * 2 + 1] = z1 - lse;
  }
}

extern "C" void kernel_launch(void* const* d_in, const int* in_sizes, int n_in,
                              void* d_out, int out_size, void* d_ws, size_t ws_size,
                              hipStream_t stream) {
  (void)in_sizes; (void)n_in; (void)out_size; (void)ws_size;
  const int*   in1  = (const int*)d_in[0];
  const int*   in2  = (const int*)d_in[1];
  const float* emb  = (const float*)d_in[2];
  const float* pos  = (const float*)d_in[3];
  const float* Wih  = (const float*)d_in[4];
  const float* Whh  = (const float*)d_in[5];
  const float* bih  = (const float*)d_in[6];
  const float* bhh  = (const float*)d_in[7];
  const float* linw = (const float*)d_in[8];
  const float* linb = (const float*)d_in[9];
  float* out = (float*)d_out;

  char* ws = (char*)d_ws;
  const size_t WPERM_B = (size_t)G4_ * KDIM * 2;   // 33,423,360
  const size_t ABUF_B  = (size_t)B_ * KDIM * 2;    // 17,825,792
  const size_t CST_B   = (size_t)B_ * H_ * 4;      // 31,457,280
  unsigned short* Wp  = (unsigned short*)(ws);
  unsigned short* A0  = (unsigned short*)(ws + WPERM_B);
  unsigned short* A1  = (unsigned short*)(ws + WPERM_B + ABUF_B);
  float*          Cst = (float*)(ws + WPERM_B + 2 * ABUF_B);
  float*          bp  = (float*)(ws + WPERM_B + 2 * ABUF_B + CST_B);

  // prep (must rerun every call: ws is re-poisoned)
  wperm_kernel<<<dim3(9, G4_), 256, 0, stream>>>(Wih, Whh, Wp);
  bias_kernel<<<dim3((G4_ + 255) / 256), 256, 0, stream>>>(bih, bhh, bp);
  zeroh_kernel<<<dim3(8, B_), 256, 0, stream>>>(A0);
  copyx_kernel<<<dim3(B_), 256, 0, stream>>>(in1, emb, pos, A0, 0);

  unsigned short* Abufs[2] = {A0, A1};
  for (int t = 0; t < SEQ_; ++t) {
    unsigned short* Acur = Abufs[t & 1];
    unsigned short* Anxt = Abufs[(t + 1) & 1];
    gemm_lstm_kernel<<<dim3((G4_ / BM) * (B_ / BM)), 512, 0, stream>>>(
        Acur, Wp, bp, Cst, Anxt, t == 0 ? 1 : 0);
    if (t + 1 < SEQ_)
      copyx_kernel<<<dim3(B_), 256, 0, stream>>>(in1, emb, pos, Anxt, t + 1);
  }
  final_kernel<<<dim3(B_), 64, 0, stream>>>(Abufs[SEQ_ & 1], in2, emb, linw, linb, out);
}